// Round 4
// baseline (746.648 us; speedup 1.0000x reference)
//
#include <hip/hip_runtime.h>
#include <hip/hip_bf16.h>

#define NSEQ 8192
#define CDIM 2048
#define NHEAD 16
#define HD 128

typedef short short8 __attribute__((ext_vector_type(8)));
typedef short short4v __attribute__((ext_vector_type(4)));
typedef float float4v __attribute__((ext_vector_type(4)));

__device__ __forceinline__ short f2bf(float f) {
    __hip_bfloat16 h = __float2bfloat16(f);
    return *reinterpret_cast<short*>(&h);
}

// async global->LDS, 16B per lane. LDS dest = wave-uniform base + lane*16B.
__device__ __forceinline__ void async_load16(const short* g, short* l) {
    __builtin_amdgcn_global_load_lds((const __attribute__((address_space(1))) void*)g,
                                     (__attribute__((address_space(3))) void*)l,
                                     16, 0, 0);
}

// ---------------------------------------------------------------------------
// fp32 -> bf16 conversion of x, Wq, Wk, Wv into workspace. 8 elems/thread.
// ---------------------------------------------------------------------------
#define X8 (33554432 / 8)   // x element-octets
#define W8 (4194304 / 8)    // per-W element-octets

__global__ __launch_bounds__(256) void cvt_all(
    const float* __restrict__ x, const float* __restrict__ wq,
    const float* __restrict__ wk, const float* __restrict__ wv,
    short* __restrict__ xb, short* __restrict__ wqb,
    short* __restrict__ wkb, short* __restrict__ wvb)
{
    const size_t i = (size_t)blockIdx.x * blockDim.x + threadIdx.x;
    const float* src;
    short* dst;
    size_t off;
    if (i < X8)              { src = x;  dst = xb;  off = i; }
    else if (i < X8 + W8)    { src = wq; dst = wqb; off = i - X8; }
    else if (i < X8 + 2*W8)  { src = wk; dst = wkb; off = i - X8 - W8; }
    else                     { src = wv; dst = wvb; off = i - X8 - 2*(size_t)W8; }
    const float4v a = ((const float4v*)src)[off * 2];
    const float4v b = ((const float4v*)src)[off * 2 + 1];
    short8 o;
    for (int j = 0; j < 4; j++) { o[j] = f2bf(a[j]); o[4 + j] = f2bf(b[j]); }
    ((short8*)dst)[off] = o;
}

// ---------------------------------------------------------------------------
// QKV projection, ONE matrix per dispatch (split for rocprof visibility of
// s2_attn; identical inner loop to R2/R3): 256x256 tile, BK=64, 8-phase
// schedule, conflict-free (row&7)<<3 LDS swizzle, counted vmcnt, setprio.
// mat==0: Q fp32 -> qout; mat==1: K bf16 [B][H][seq][d]; mat==2: V bf16
// TRANSPOSED [B][H][d][seq].
// ---------------------------------------------------------------------------
#define PBAR()  asm volatile("s_barrier" ::: "memory")
#define LGKM0() do { asm volatile("s_waitcnt lgkmcnt(0)" ::: "memory"); \
                     __builtin_amdgcn_sched_barrier(0); } while (0)
#define VMC4()  asm volatile("s_waitcnt vmcnt(4)" ::: "memory")
#define VMC0()  asm volatile("s_waitcnt vmcnt(0)" ::: "memory")

#define MFMA(d, x, y) d = __builtin_amdgcn_mfma_f32_16x16x32_bf16(x, y, d, 0, 0, 0)

__global__ __launch_bounds__(512, 2) void qkv_gemm8(
    const short* __restrict__ xb,
    const short* __restrict__ W, const float* __restrict__ bias,
    float* __restrict__ qout, short* __restrict__ kt, short* __restrict__ vt,
    const int mat)
{
    __shared__ short lds[2][2][256 * 64];   // 128 KiB

    const int tid  = threadIdx.x;
    const int w    = tid >> 6;
    const int lane = tid & 63;
    const int quad = lane >> 4;
    const int l15  = lane & 15;
    const int wm   = w >> 2;     // 0..1
    const int wn   = w & 3;      // 0..3

    // T1: bijective XCD swizzle (512 blocks, 512 % 8 == 0).
    // Consecutive ids share the A-panel (8 ntiles per mtile).
    const int id    = (blockIdx.x & 7) * 64 + (blockIdx.x >> 3);
    const int mtile = id >> 3;   // 0..63
    const int ntile = id & 7;
    const int M0 = mtile << 8;
    const int N0 = ntile << 8;

    const short* Ab = xb + (size_t)M0 * CDIM;
    const short* Bb = W  + (size_t)N0 * CDIM;

    const int stg_row = tid >> 3;
    const int stg_col = ((tid & 7) * 8) ^ (((tid >> 3) & 7) << 3);
    const int cswz    = (lane & 7) << 3;   // read swizzle: row&7 == l15&7

    float bvals[4];
#pragma unroll
    for (int j = 0; j < 4; ++j)
        bvals[j] = bias[N0 + wn * 64 + j * 16 + l15];
    VMC0();

    float4v acc[8][4];
#pragma unroll
    for (int i = 0; i < 8; ++i)
#pragma unroll
        for (int j = 0; j < 4; ++j)
            acc[i][j] = (float4v){0.f, 0.f, 0.f, 0.f};

    auto stage = [&](int bufi, int ab, int h, int t, const short* src) {
        short* l0 = &lds[bufi][ab][h * 8192 + w * 512];
        const short* g = src + (size_t)(h * 128 + stg_row) * CDIM + t * 64 + stg_col;
        async_load16(g, l0);                            // rows [h*128,      +64)
        async_load16(g + (size_t)64 * CDIM, l0 + 4096); // rows [h*128+64, +128)
    };
    auto ldA = [&](int bufi, int i, int ks) -> short8 {
        const int row = wm * 128 + i * 16 + l15;
        return *(const short8*)&lds[bufi][0][row * 64 + ((ks * 32 + quad * 8) ^ cswz)];
    };
    auto ldB = [&](int bufi, int j, int ks) -> short8 {
        const int row = wn * 64 + j * 16 + l15;
        return *(const short8*)&lds[bufi][1][row * 64 + ((ks * 32 + quad * 8) ^ cswz)];
    };

    // prologue: tile0 (A+B) -> buf0; tile1 B -> buf1. Wait buf0 (8 oldest).
    stage(0, 0, 0, 0, Ab); stage(0, 0, 1, 0, Ab);
    stage(0, 1, 0, 0, Bb); stage(0, 1, 1, 0, Bb);
    stage(1, 1, 0, 1, Bb); stage(1, 1, 1, 1, Bb);
    VMC4();
    PBAR();

    short8 a[4][2], b[4][2];
    for (int it = 0; it < 16; ++it) {
        const int t1 = 2 * it + 1;
        const int t2 = (2 * it + 2 > 31) ? 31 : 2 * it + 2;
        const int t3 = (2 * it + 3 > 31) ? 31 : 2 * it + 3;

        // ---- phase 1: buf0 (m-half0, n-half0); stage buf1.A <- t1 ----
#pragma unroll
        for (int i = 0; i < 4; ++i) { a[i][0] = ldA(0, i, 0); a[i][1] = ldA(0, i, 1); }
#pragma unroll
        for (int j = 0; j < 2; ++j) { b[j][0] = ldB(0, j, 0); b[j][1] = ldB(0, j, 1); }
        stage(1, 0, 0, t1, Ab); stage(1, 0, 1, t1, Ab);
        PBAR(); LGKM0();
        __builtin_amdgcn_s_setprio(1);
#pragma unroll
        for (int i = 0; i < 4; ++i)
#pragma unroll
            for (int j = 0; j < 2; ++j) { MFMA(acc[i][j], a[i][0], b[j][0]);
                                          MFMA(acc[i][j], a[i][1], b[j][1]); }
        __builtin_amdgcn_s_setprio(0);
        PBAR();

        // ---- phase 2: buf0 (m-half0, n-half1) ----
#pragma unroll
        for (int j = 2; j < 4; ++j) { b[j][0] = ldB(0, j, 0); b[j][1] = ldB(0, j, 1); }
        PBAR(); LGKM0();
        __builtin_amdgcn_s_setprio(1);
#pragma unroll
        for (int i = 0; i < 4; ++i)
#pragma unroll
            for (int j = 2; j < 4; ++j) { MFMA(acc[i][j], a[i][0], b[j][0]);
                                          MFMA(acc[i][j], a[i][1], b[j][1]); }
        __builtin_amdgcn_s_setprio(0);
        PBAR();

        // ---- phase 3: buf0 (m-half1, n-half1); stage buf0.B.h0 <- t2 ----
#pragma unroll
        for (int i = 0; i < 4; ++i) { a[i][0] = ldA(0, 4 + i, 0); a[i][1] = ldA(0, 4 + i, 1); }
        stage(0, 1, 0, t2, Bb);
        PBAR(); LGKM0();
        __builtin_amdgcn_s_setprio(1);
#pragma unroll
        for (int i = 0; i < 4; ++i)
#pragma unroll
            for (int j = 2; j < 4; ++j) { MFMA(acc[4 + i][j], a[i][0], b[j][0]);
                                          MFMA(acc[4 + i][j], a[i][1], b[j][1]); }
        __builtin_amdgcn_s_setprio(0);
        PBAR();

        // ---- phase 4: buf0 (m-half1, n-half0); stage buf0.B.h1; vmcnt(4) ----
        stage(0, 1, 1, t2, Bb);
        PBAR(); LGKM0();
        __builtin_amdgcn_s_setprio(1);
#pragma unroll
        for (int i = 0; i < 4; ++i)
#pragma unroll
            for (int j = 0; j < 2; ++j) { MFMA(acc[4 + i][j], a[i][0], b[j][0]);
                                          MFMA(acc[4 + i][j], a[i][1], b[j][1]); }
        __builtin_amdgcn_s_setprio(0);
        VMC4();               // confirms buf1 (tile 2it+1) fully staged
        PBAR();

        // ---- phase 5: buf1 (m-half0, n-half0); stage buf0.A <- t2 ----
#pragma unroll
        for (int i = 0; i < 4; ++i) { a[i][0] = ldA(1, i, 0); a[i][1] = ldA(1, i, 1); }
#pragma unroll
        for (int j = 0; j < 2; ++j) { b[j][0] = ldB(1, j, 0); b[j][1] = ldB(1, j, 1); }
        stage(0, 0, 0, t2, Ab); stage(0, 0, 1, t2, Ab);
        PBAR(); LGKM0();
        __builtin_amdgcn_s_setprio(1);
#pragma unroll
        for (int i = 0; i < 4; ++i)
#pragma unroll
            for (int j = 0; j < 2; ++j) { MFMA(acc[i][j], a[i][0], b[j][0]);
                                          MFMA(acc[i][j], a[i][1], b[j][1]); }
        __builtin_amdgcn_s_setprio(0);
        PBAR();

        // ---- phase 6: buf1 (m-half0, n-half1) ----
#pragma unroll
        for (int j = 2; j < 4; ++j) { b[j][0] = ldB(1, j, 0); b[j][1] = ldB(1, j, 1); }
        PBAR(); LGKM0();
        __builtin_amdgcn_s_setprio(1);
#pragma unroll
        for (int i = 0; i < 4; ++i)
#pragma unroll
            for (int j = 2; j < 4; ++j) { MFMA(acc[i][j], a[i][0], b[j][0]);
                                          MFMA(acc[i][j], a[i][1], b[j][1]); }
        __builtin_amdgcn_s_setprio(0);
        PBAR();

        // ---- phase 7: buf1 (m-half1, n-half1); stage buf1.B.h0 <- t3 ----
#pragma unroll
        for (int i = 0; i < 4; ++i) { a[i][0] = ldA(1, 4 + i, 0); a[i][1] = ldA(1, 4 + i, 1); }
        stage(1, 1, 0, t3, Bb);
        PBAR(); LGKM0();
        __builtin_amdgcn_s_setprio(1);
#pragma unroll
        for (int i = 0; i < 4; ++i)
#pragma unroll
            for (int j = 2; j < 4; ++j) { MFMA(acc[4 + i][j], a[i][0], b[j][0]);
                                          MFMA(acc[4 + i][j], a[i][1], b[j][1]); }
        __builtin_amdgcn_s_setprio(0);
        PBAR();

        // ---- phase 8: buf1 (m-half1, n-half0); stage buf1.B.h1; vmcnt(4) ----
        stage(1, 1, 1, t3, Bb);
        PBAR(); LGKM0();
        __builtin_amdgcn_s_setprio(1);
#pragma unroll
        for (int i = 0; i < 4; ++i)
#pragma unroll
            for (int j = 0; j < 2; ++j) { MFMA(acc[4 + i][j], a[i][0], b[j][0]);
                                          MFMA(acc[4 + i][j], a[i][1], b[j][1]); }
        __builtin_amdgcn_s_setprio(0);
        VMC4();               // confirms buf0 (tile 2it+2) fully staged
        PBAR();
    }

    // epilogue. C/D layout: row = quad*4 + r (m), col = l15 (n).
#pragma unroll
    for (int j = 0; j < 4; ++j) {
        const int n = N0 + wn * 64 + j * 16 + l15;
        if (mat == 0) {
#pragma unroll
            for (int i = 0; i < 8; ++i) {
                const int mrow = M0 + wm * 128 + i * 16 + quad * 4;
#pragma unroll
                for (int r = 0; r < 4; ++r)
                    qout[((size_t)(mrow + r) << 11) + n] = acc[i][j][r] + bvals[j];
            }
        } else if (mat == 1) {
            // K: [B][H][seq][d]
            const int h = n >> 7;
            const int d = n & (HD - 1);
#pragma unroll
            for (int i = 0; i < 8; ++i) {
                const int mrow = M0 + wm * 128 + i * 16 + quad * 4;
#pragma unroll
                for (int r = 0; r < 4; ++r) {
                    const int m  = mrow + r;
                    const int bb = m >> 13;
                    const int sq = m & (NSEQ - 1);
                    kt[(((size_t)(bb * NHEAD + h) * NSEQ + sq) << 7) + d] =
                        f2bf(acc[i][j][r] + bvals[j]);
                }
            }
        } else {
            // V transposed: [B][H][d][seq] -- short4 stores (4 consecutive seq)
            const int h = n >> 7;
            const int d = n & (HD - 1);
#pragma unroll
            for (int i = 0; i < 8; ++i) {
                const int mrow = M0 + wm * 128 + i * 16 + quad * 4;
                const int bb = mrow >> 13;
                const int sq = mrow & (NSEQ - 1);
                short4v o4;
#pragma unroll
                for (int r = 0; r < 4; ++r) o4[r] = f2bf(acc[i][j][r] + bvals[j]);
                *(short4v*)&vt[(((size_t)(bb * NHEAD + h) * HD + d) << 13) + sq] = o4;
            }
        }
    }
}

// ---------------------------------------------------------------------------
// Group-local causal attention, S2 shift via index arithmetic.
// R4: causal work-skip. Wave w owns tiles {w, w+8} (im=0/1). Activity at
// 32-key-half granularity: half-unit u = 4*kc + 2*h is active for tile mt
// iff u <= mt (first key of half <= last q row). QK^T / softmax / Ps / PV
// all use the SAME half-aligned condition, so Ps is always fully written
// before any pf read of that half. Saves 44% of MFMA+VALU vs full rect.
// Chunk pipeline from R3 kept: K reg-prefetch + V global_load_lds dbuf,
// 2 barriers/chunk, wave-private Ps with lgkmcnt-only sync.
// ---------------------------------------------------------------------------
__global__ __launch_bounds__(512, 1) void s2_attn(const float* qsrc,   // aliases out!
                                                  const short* __restrict__ kt,
                                                  const short* __restrict__ vt,
                                                  float* out)
{
    __shared__ short Ks[64 * 136];       // K chunk, row-major, +8 pad
    __shared__ short Vt[2][128 * 64];    // V^T chunks: [d][kv], XOR-swizzled, dbuf
    __shared__ short Ps[8][32 * 40];     // per-wave P: 32 q-rows x 32 keys

    const int bx = blockIdx.x;
    const int g  = bx & 31;
    const int h  = (bx >> 5) & 15;
    const int b  = bx >> 9;
    const int shift = (h >= 8) ? 128 : 0;
    const int sbase = g * 256 + shift;   // group-local i -> seq p = (sbase+i)&8191

    const int tid  = threadIdx.x;
    const int wave = tid >> 6;
    const int lane = tid & 63;
    const int quad = lane >> 4;
    const int l15  = lane & 15;

    const size_t bh = ((size_t)b * NHEAD + h) * NSEQ;
    const short* kg = kt + bh * HD;
    const short* vg = vt + bh * HD;      // base of [d][seq] block for (b,h)

    // wave w owns m-tiles w (im=0) and w+8 (im=1)
    const int mtA = wave;
    const int mtB = wave + 8;

    // V stage geometry: 8 d-rows per wave per call, 64 kv cols; global seq
    // col pre-swizzled by (d&7)<<3 (matches swizzled b128 read below).
    const int vrow_in_w = lane >> 3;                       // == d&7
    const int vgcol     = ((lane & 7) * 8) ^ (vrow_in_w << 3);
    // K stage geometry
    const int krow0 = tid >> 4;          // rows krow0 and krow0+32
    const int kcolb = (tid & 15) * 8;

    short8 kr0, kr1;                     // K prefetch registers (static names)

    // --- prologue: issue chunk-0 V async + K reg loads, then Q frags ---
    {
        const int p = (sbase + vgcol) & (NSEQ - 1);
#pragma unroll
        for (int c = 0; c < 2; c++) {
            const int d = c * 64 + wave * 8 + vrow_in_w;
            async_load16(vg + (size_t)d * NSEQ + p, &Vt[0][(c * 64 + wave * 8) * 64]);
        }
        const int p0 = (sbase + krow0) & (NSEQ - 1);
        const int p1 = (sbase + krow0 + 32) & (NSEQ - 1);
        kr0 = *(const short8*)(kg + (size_t)p0 * HD + kcolb);
        kr1 = *(const short8*)(kg + (size_t)p1 * HD + kcolb);
    }

    // Q fragments from fp32 d_out (A-layout: m=l15, k=quad*8+j)
    short8 qf[2][4];
#pragma unroll
    for (int im = 0; im < 2; im++) {
        const int mt  = im ? mtB : mtA;
        const int row = mt * 16 + l15;
        const int p   = (sbase + row) & (NSEQ - 1);
        const float* qr = qsrc + (((size_t)(b * NSEQ + p)) << 11) + h * HD;
#pragma unroll
        for (int ks = 0; ks < 4; ks++) {
            const float4v qa = *(const float4v*)(qr + ks * 32 + quad * 8);
            const float4v qb = *(const float4v*)(qr + ks * 32 + quad * 8 + 4);
            short8 f;
#pragma unroll
            for (int j = 0; j < 4; j++) { f[j] = f2bf(qa[j]); f[4 + j] = f2bf(qb[j]); }
            qf[im][ks] = f;
        }
    }

    const float4v fzero = {0.f, 0.f, 0.f, 0.f};
    float4v o[2][8];
#pragma unroll
    for (int im = 0; im < 2; im++)
#pragma unroll
        for (int dt = 0; dt < 8; dt++)
            o[im][dt] = fzero;
    float rs[2][4] = {{0.f, 0.f, 0.f, 0.f}, {0.f, 0.f, 0.f, 0.f}};

    for (int kc = 0; kc < 4; kc++) {
        // --- chunk top: V[kc] (LDS) and K[kc] (regs) needed now; latency
        // was hidden under chunk kc-1's compute. ---
        VMC0();
        *(short8*)&Ks[krow0 * 136 + kcolb]        = kr0;
        *(short8*)&Ks[(krow0 + 32) * 136 + kcolb] = kr1;
        LGKM0();
        PBAR();                          // all waves: Ks written, V[kc] in LDS

        // --- prefetch chunk kc+1 (V async into other buffer; K into regs) ---
        if (kc < 3) {
            const int p = (sbase + (kc + 1) * 64 + vgcol) & (NSEQ - 1);
#pragma unroll
            for (int c = 0; c < 2; c++) {
                const int d = c * 64 + wave * 8 + vrow_in_w;
                async_load16(vg + (size_t)d * NSEQ + p,
                             &Vt[(kc + 1) & 1][(c * 64 + wave * 8) * 64]);
            }
            const int p0 = (sbase + (kc + 1) * 64 + krow0) & (NSEQ - 1);
            const int p1 = (sbase + (kc + 1) * 64 + krow0 + 32) & (NSEQ - 1);
            kr0 = *(const short8*)(kg + (size_t)p0 * HD + kcolb);
            kr1 = *(const short8*)(kg + (size_t)p1 * HD + kcolb);
        }

        // half-unit activity (wave-uniform): u = 4kc + 2h <= mt
        const bool hA[2] = {(4 * kc)     <= mtA, (4 * kc + 2) <= mtA};
        const bool hB[2] = {(4 * kc)     <= mtB, (4 * kc + 2) <= mtB};

        // --- scores (half-aligned skip; mtB superset of mtA) ---
        float4v s[2][4];
#pragma unroll
        for (int im = 0; im < 2; im++)
#pragma unroll
            for (int nn = 0; nn < 4; nn++)
                s[im][nn] = fzero;
        __builtin_amdgcn_s_setprio(1);
#pragma unroll
        for (int nn = 0; nn < 4; nn++) {
            const int hh = nn >> 1;
            if (hB[hh]) {
                short8 kf[4];
#pragma unroll
                for (int ks = 0; ks < 4; ks++)
                    kf[ks] = *(const short8*)&Ks[(nn * 16 + l15) * 136 + ks * 32 + quad * 8];
                if (hA[hh]) {
#pragma unroll
                    for (int ks = 0; ks < 4; ks++)
                        s[0][nn] = __builtin_amdgcn_mfma_f32_16x16x32_bf16(
                            qf[0][ks], kf[ks], s[0][nn], 0, 0, 0);
                }
#pragma unroll
                for (int ks = 0; ks < 4; ks++)
                    s[1][nn] = __builtin_amdgcn_mfma_f32_16x16x32_bf16(
                        qf[1][ks], kf[ks], s[1][nn], 0, 0, 0);
            }
        }
        __builtin_amdgcn_s_setprio(0);

        // --- exp + P (wave-private LDS) + PV, per active 32-key half ---
#pragma unroll
        for (int half = 0; half < 2; half++) {
            if (!hB[half]) continue;     // hB superset of hA
#pragma unroll
            for (int im = 0; im < 2; im++) {
                if (im == 0 && !hA[half]) continue;
                const int mt   = im ? mtB : mtA;
                const int qpos = mt * 16 + quad * 4;               // group-abs q row (+r)
#pragma unroll
                for (int nn2 = 0; nn2 < 2; nn2++) {
                    const int nn   = half * 2 + nn2;
                    const int kpos = kc * 64 + nn * 16 + l15;      // group-abs key
#pragma unroll
                    for (int r = 0; r < 4; r++) {
                        const float sv = s[im][nn][r] * 0.088388347648318447f;
                        const float pv = (kpos > qpos + r)
                                             ? 0.f
                                             : __expf(fminf(sv, 30.f));
                        rs[im][r] += pv;
                        Ps[wave][(im * 16 + quad * 4 + r) * 40 + nn2 * 16 + l15] = f2bf(pv);
                    }
                }
            }
            LGKM0();                     // wave-private Ps: writes -> reads
            short8 pf[2];
            if (hA[half])
                pf[0] = *(const short8*)&Ps[wave][(0 * 16 + l15) * 40 + quad * 8];
            pf[1] = *(const short8*)&Ps[wave][(1 * 16 + l15) * 40 + quad * 8];
            __builtin_amdgcn_s_setprio(1);
#pragma unroll
            for (int dt = 0; dt < 8; dt++) {
                const int d = dt * 16 + l15;        // d&7 == l15&7
                const short8 vf = *(const short8*)
                    &Vt[kc & 1][d * 64 + ((half * 32 + quad * 8) ^ ((l15 & 7) << 3))];
                if (hA[half])
                    o[0][dt] = __builtin_amdgcn_mfma_f32_16x16x32_bf16(
                        pf[0], vf, o[0][dt], 0, 0, 0);
                o[1][dt] = __builtin_amdgcn_mfma_f32_16x16x32_bf16(
                    pf[1], vf, o[1][dt], 0, 0, 0);
            }
            __builtin_amdgcn_s_setprio(0);
        }
        PBAR();                          // chunk end: Ks readers done, V[kc] done
    }

    // row sums: reduce across the 16 l15 lanes of each quad
#pragma unroll
    for (int im = 0; im < 2; im++)
#pragma unroll
        for (int r = 0; r < 4; r++) {
            float v = rs[im][r];
            v += __shfl_xor(v, 1);
            v += __shfl_xor(v, 2);
            v += __shfl_xor(v, 4);
            v += __shfl_xor(v, 8);
            rs[im][r] = v;
        }

    // write output fp32 [B][N][C]; un-shift == same p mapping
#pragma unroll
    for (int im = 0; im < 2; im++) {
        const int mt = im ? mtB : mtA;
#pragma unroll
        for (int r = 0; r < 4; r++) {
            const int row = mt * 16 + quad * 4 + r;
            const int p   = (sbase + row) & (NSEQ - 1);
            const float inv = 1.f / rs[im][r];
            const size_t obase = (((size_t)(b * NSEQ + p)) << 11) + h * HD;
#pragma unroll
            for (int dt = 0; dt < 8; dt++)
                out[obase + dt * 16 + l15] = o[im][dt][r] * inv;
        }
    }
}

extern "C" void kernel_launch(void* const* d_in, const int* in_sizes, int n_in,
                              void* d_out, int out_size, void* d_ws, size_t ws_size,
                              hipStream_t stream) {
    (void)in_sizes; (void)n_in; (void)out_size; (void)ws_size;
    const float* x  = (const float*)d_in[0];
    const float* Wq = (const float*)d_in[1];
    const float* bq = (const float*)d_in[2];
    const float* Wk = (const float*)d_in[3];
    const float* bk = (const float*)d_in[4];
    const float* Wv = (const float*)d_in[5];
    const float* bv = (const float*)d_in[6];

    // ws layout (bf16 shorts): xb | wqb | wkb | wvb | kt | vt  (~216 MiB)
    short* xb  = (short*)d_ws;
    short* wqb = xb  + (size_t)33554432;
    short* wkb = wqb + (size_t)4194304;
    short* wvb = wkb + (size_t)4194304;
    short* kt  = wvb + (size_t)4194304;
    short* vt  = kt  + (size_t)33554432;

    float* outp = (float*)d_out;

    cvt_all<<<dim3(22528), 256, 0, stream>>>(x, Wq, Wk, Wv, xb, wqb, wkb, wvb);
    qkv_gemm8<<<dim3(512), 512, 0, stream>>>(xb, wqb, bq, outp, kt, vt, 0);
    qkv_gemm8<<<dim3(512), 512, 0, stream>>>(xb, wkb, bk, outp, kt, vt, 1);
    qkv_gemm8<<<dim3(512), 512, 0, stream>>>(xb, wvb, bv, outp, kt, vt, 2);
    s2_attn<<<dim3(1024), 512, 0, stream>>>(outp, kt, vt, outp);
}

// Round 5
// 726.548 us; speedup vs baseline: 1.0277x; 1.0277x over previous
//
#include <hip/hip_runtime.h>
#include <hip/hip_bf16.h>

#define NSEQ 8192
#define CDIM 2048
#define NHEAD 16
#define HD 128

typedef short short8 __attribute__((ext_vector_type(8)));
typedef short short4v __attribute__((ext_vector_type(4)));
typedef float float4v __attribute__((ext_vector_type(4)));

__device__ __forceinline__ short f2bf(float f) {
    __hip_bfloat16 h = __float2bfloat16(f);
    return *reinterpret_cast<short*>(&h);
}

// async global->LDS, 16B per lane. LDS dest = wave-uniform base + lane*16B.
__device__ __forceinline__ void async_load16(const short* g, short* l) {
    __builtin_amdgcn_global_load_lds((const __attribute__((address_space(1))) void*)g,
                                     (__attribute__((address_space(3))) void*)l,
                                     16, 0, 0);
}

// ---------------------------------------------------------------------------
// fp32 -> bf16 conversion of x, Wq, Wk, Wv into workspace.
// R5 rewrite: grid-stride, 2048 blocks (G11), 16 elems (64B read / 32B write)
// per thread-iteration -> ~5.5 iterations/thread, loop-pipelined ILP.
// (R0-R4 version: 22528 one-shot blocks, measured ~148us vs 44us roofline.)
// ---------------------------------------------------------------------------
#define X16 (33554432 / 16)   // x element-16-groups
#define W16 (4194304 / 16)    // per-W element-16-groups
#define TOT16 (X16 + 3 * W16)

__global__ __launch_bounds__(256) void cvt_all(
    const float* __restrict__ x, const float* __restrict__ wq,
    const float* __restrict__ wk, const float* __restrict__ wv,
    short* __restrict__ xb, short* __restrict__ wqb,
    short* __restrict__ wkb, short* __restrict__ wvb)
{
    const size_t stride = (size_t)gridDim.x * blockDim.x;
    for (size_t i = (size_t)blockIdx.x * blockDim.x + threadIdx.x;
         i < (size_t)TOT16; i += stride) {
        const float* src;
        short* dst;
        size_t off;
        if (i < X16)                 { src = x;  dst = xb;  off = i; }
        else if (i < X16 + W16)      { src = wq; dst = wqb; off = i - X16; }
        else if (i < X16 + 2 * W16)  { src = wk; dst = wkb; off = i - X16 - W16; }
        else                         { src = wv; dst = wvb; off = i - X16 - 2 * (size_t)W16; }
        const float4v* s4 = (const float4v*)src + off * 4;
        const float4v a0 = s4[0], a1 = s4[1], a2 = s4[2], a3 = s4[3];
        short8 o0, o1;
#pragma unroll
        for (int j = 0; j < 4; j++) {
            o0[j]     = f2bf(a0[j]);
            o0[4 + j] = f2bf(a1[j]);
            o1[j]     = f2bf(a2[j]);
            o1[4 + j] = f2bf(a3[j]);
        }
        short8* d8 = (short8*)dst + off * 2;
        d8[0] = o0;
        d8[1] = o1;
    }
}

// ---------------------------------------------------------------------------
// Fused QKV projection (merged back, R3-identical body): 256x256 tile, BK=64,
// 8-phase schedule, conflict-free (row&7)<<3 LDS swizzle, counted vmcnt,
// setprio. 1536 blocks (3 mats x 512). V written TRANSPOSED [B][H][d][seq].
// ---------------------------------------------------------------------------
#define PBAR()  asm volatile("s_barrier" ::: "memory")
#define LGKM0() do { asm volatile("s_waitcnt lgkmcnt(0)" ::: "memory"); \
                     __builtin_amdgcn_sched_barrier(0); } while (0)
#define VMC4()  asm volatile("s_waitcnt vmcnt(4)" ::: "memory")
#define VMC0()  asm volatile("s_waitcnt vmcnt(0)" ::: "memory")

#define MFMA(d, x, y) d = __builtin_amdgcn_mfma_f32_16x16x32_bf16(x, y, d, 0, 0, 0)

__global__ __launch_bounds__(512, 2) void qkv_gemm8(
    const short* __restrict__ xb,
    const short* __restrict__ Wq, const float* __restrict__ bq,
    const short* __restrict__ Wk, const float* __restrict__ bk,
    const short* __restrict__ Wv, const float* __restrict__ bv,
    float* __restrict__ qout, short* __restrict__ kt, short* __restrict__ vt)
{
    __shared__ short lds[2][2][256 * 64];   // 128 KiB

    const int tid  = threadIdx.x;
    const int w    = tid >> 6;
    const int lane = tid & 63;
    const int quad = lane >> 4;
    const int l15  = lane & 15;
    const int wm   = w >> 2;     // 0..1
    const int wn   = w & 3;      // 0..3

    // T1: bijective XCD swizzle (1536 blocks, 1536 % 8 == 0).
    const int id    = (blockIdx.x & 7) * 192 + (blockIdx.x >> 3);
    const int mtile = id / 24;
    const int rest  = id - mtile * 24;
    const int mat   = rest >> 3;
    const int ntile = rest & 7;
    const int M0 = mtile << 8;
    const int N0 = ntile << 8;

    const short* W    = (mat == 0) ? Wq : (mat == 1) ? Wk : Wv;
    const float* bias = (mat == 0) ? bq : (mat == 1) ? bk : bv;
    const short* Ab = xb + (size_t)M0 * CDIM;
    const short* Bb = W  + (size_t)N0 * CDIM;

    const int stg_row = tid >> 3;
    const int stg_col = ((tid & 7) * 8) ^ (((tid >> 3) & 7) << 3);
    const int cswz    = (lane & 7) << 3;   // read swizzle: row&7 == l15&7

    float bvals[4];
#pragma unroll
    for (int j = 0; j < 4; ++j)
        bvals[j] = bias[N0 + wn * 64 + j * 16 + l15];
    VMC0();

    float4v acc[8][4];
#pragma unroll
    for (int i = 0; i < 8; ++i)
#pragma unroll
        for (int j = 0; j < 4; ++j)
            acc[i][j] = (float4v){0.f, 0.f, 0.f, 0.f};

    auto stage = [&](int bufi, int ab, int h, int t, const short* src) {
        short* l0 = &lds[bufi][ab][h * 8192 + w * 512];
        const short* g = src + (size_t)(h * 128 + stg_row) * CDIM + t * 64 + stg_col;
        async_load16(g, l0);                            // rows [h*128,      +64)
        async_load16(g + (size_t)64 * CDIM, l0 + 4096); // rows [h*128+64, +128)
    };
    auto ldA = [&](int bufi, int i, int ks) -> short8 {
        const int row = wm * 128 + i * 16 + l15;
        return *(const short8*)&lds[bufi][0][row * 64 + ((ks * 32 + quad * 8) ^ cswz)];
    };
    auto ldB = [&](int bufi, int j, int ks) -> short8 {
        const int row = wn * 64 + j * 16 + l15;
        return *(const short8*)&lds[bufi][1][row * 64 + ((ks * 32 + quad * 8) ^ cswz)];
    };

    // prologue: tile0 (A+B) -> buf0; tile1 B -> buf1. Wait buf0 (8 oldest).
    stage(0, 0, 0, 0, Ab); stage(0, 0, 1, 0, Ab);
    stage(0, 1, 0, 0, Bb); stage(0, 1, 1, 0, Bb);
    stage(1, 1, 0, 1, Bb); stage(1, 1, 1, 1, Bb);
    VMC4();
    PBAR();

    short8 a[4][2], b[4][2];
    for (int it = 0; it < 16; ++it) {
        const int t1 = 2 * it + 1;
        const int t2 = (2 * it + 2 > 31) ? 31 : 2 * it + 2;
        const int t3 = (2 * it + 3 > 31) ? 31 : 2 * it + 3;

        // ---- phase 1: buf0 (m-half0, n-half0); stage buf1.A <- t1 ----
#pragma unroll
        for (int i = 0; i < 4; ++i) { a[i][0] = ldA(0, i, 0); a[i][1] = ldA(0, i, 1); }
#pragma unroll
        for (int j = 0; j < 2; ++j) { b[j][0] = ldB(0, j, 0); b[j][1] = ldB(0, j, 1); }
        stage(1, 0, 0, t1, Ab); stage(1, 0, 1, t1, Ab);
        PBAR(); LGKM0();
        __builtin_amdgcn_s_setprio(1);
#pragma unroll
        for (int i = 0; i < 4; ++i)
#pragma unroll
            for (int j = 0; j < 2; ++j) { MFMA(acc[i][j], a[i][0], b[j][0]);
                                          MFMA(acc[i][j], a[i][1], b[j][1]); }
        __builtin_amdgcn_s_setprio(0);
        PBAR();

        // ---- phase 2: buf0 (m-half0, n-half1) ----
#pragma unroll
        for (int j = 2; j < 4; ++j) { b[j][0] = ldB(0, j, 0); b[j][1] = ldB(0, j, 1); }
        PBAR(); LGKM0();
        __builtin_amdgcn_s_setprio(1);
#pragma unroll
        for (int i = 0; i < 4; ++i)
#pragma unroll
            for (int j = 2; j < 4; ++j) { MFMA(acc[i][j], a[i][0], b[j][0]);
                                          MFMA(acc[i][j], a[i][1], b[j][1]); }
        __builtin_amdgcn_s_setprio(0);
        PBAR();

        // ---- phase 3: buf0 (m-half1, n-half1); stage buf0.B.h0 <- t2 ----
#pragma unroll
        for (int i = 0; i < 4; ++i) { a[i][0] = ldA(0, 4 + i, 0); a[i][1] = ldA(0, 4 + i, 1); }
        stage(0, 1, 0, t2, Bb);
        PBAR(); LGKM0();
        __builtin_amdgcn_s_setprio(1);
#pragma unroll
        for (int i = 0; i < 4; ++i)
#pragma unroll
            for (int j = 2; j < 4; ++j) { MFMA(acc[4 + i][j], a[i][0], b[j][0]);
                                          MFMA(acc[4 + i][j], a[i][1], b[j][1]); }
        __builtin_amdgcn_s_setprio(0);
        PBAR();

        // ---- phase 4: buf0 (m-half1, n-half0); stage buf0.B.h1; vmcnt(4) ----
        stage(0, 1, 1, t2, Bb);
        PBAR(); LGKM0();
        __builtin_amdgcn_s_setprio(1);
#pragma unroll
        for (int i = 0; i < 4; ++i)
#pragma unroll
            for (int j = 0; j < 2; ++j) { MFMA(acc[4 + i][j], a[i][0], b[j][0]);
                                          MFMA(acc[4 + i][j], a[i][1], b[j][1]); }
        __builtin_amdgcn_s_setprio(0);
        VMC4();               // confirms buf1 (tile 2it+1) fully staged
        PBAR();

        // ---- phase 5: buf1 (m-half0, n-half0); stage buf0.A <- t2 ----
#pragma unroll
        for (int i = 0; i < 4; ++i) { a[i][0] = ldA(1, i, 0); a[i][1] = ldA(1, i, 1); }
#pragma unroll
        for (int j = 0; j < 2; ++j) { b[j][0] = ldB(1, j, 0); b[j][1] = ldB(1, j, 1); }
        stage(0, 0, 0, t2, Ab); stage(0, 0, 1, t2, Ab);
        PBAR(); LGKM0();
        __builtin_amdgcn_s_setprio(1);
#pragma unroll
        for (int i = 0; i < 4; ++i)
#pragma unroll
            for (int j = 0; j < 2; ++j) { MFMA(acc[i][j], a[i][0], b[j][0]);
                                          MFMA(acc[i][j], a[i][1], b[j][1]); }
        __builtin_amdgcn_s_setprio(0);
        PBAR();

        // ---- phase 6: buf1 (m-half0, n-half1) ----
#pragma unroll
        for (int j = 2; j < 4; ++j) { b[j][0] = ldB(1, j, 0); b[j][1] = ldB(1, j, 1); }
        PBAR(); LGKM0();
        __builtin_amdgcn_s_setprio(1);
#pragma unroll
        for (int i = 0; i < 4; ++i)
#pragma unroll
            for (int j = 2; j < 4; ++j) { MFMA(acc[i][j], a[i][0], b[j][0]);
                                          MFMA(acc[i][j], a[i][1], b[j][1]); }
        __builtin_amdgcn_s_setprio(0);
        PBAR();

        // ---- phase 7: buf1 (m-half1, n-half1); stage buf1.B.h0 <- t3 ----
#pragma unroll
        for (int i = 0; i < 4; ++i) { a[i][0] = ldA(1, 4 + i, 0); a[i][1] = ldA(1, 4 + i, 1); }
        stage(1, 1, 0, t3, Bb);
        PBAR(); LGKM0();
        __builtin_amdgcn_s_setprio(1);
#pragma unroll
        for (int i = 0; i < 4; ++i)
#pragma unroll
            for (int j = 2; j < 4; ++j) { MFMA(acc[4 + i][j], a[i][0], b[j][0]);
                                          MFMA(acc[4 + i][j], a[i][1], b[j][1]); }
        __builtin_amdgcn_s_setprio(0);
        PBAR();

        // ---- phase 8: buf1 (m-half1, n-half0); stage buf1.B.h1; vmcnt(4) ----
        stage(1, 1, 1, t3, Bb);
        PBAR(); LGKM0();
        __builtin_amdgcn_s_setprio(1);
#pragma unroll
        for (int i = 0; i < 4; ++i)
#pragma unroll
            for (int j = 0; j < 2; ++j) { MFMA(acc[4 + i][j], a[i][0], b[j][0]);
                                          MFMA(acc[4 + i][j], a[i][1], b[j][1]); }
        __builtin_amdgcn_s_setprio(0);
        VMC4();               // confirms buf0 (tile 2it+2) fully staged
        PBAR();
    }

    // epilogue. C/D layout: row = quad*4 + r (m), col = l15 (n).
#pragma unroll
    for (int j = 0; j < 4; ++j) {
        const int n = N0 + wn * 64 + j * 16 + l15;
        if (mat == 0) {
#pragma unroll
            for (int i = 0; i < 8; ++i) {
                const int mrow = M0 + wm * 128 + i * 16 + quad * 4;
#pragma unroll
                for (int r = 0; r < 4; ++r)
                    qout[((size_t)(mrow + r) << 11) + n] = acc[i][j][r] + bvals[j];
            }
        } else if (mat == 1) {
            // K: [B][H][seq][d]
            const int h = n >> 7;
            const int d = n & (HD - 1);
#pragma unroll
            for (int i = 0; i < 8; ++i) {
                const int mrow = M0 + wm * 128 + i * 16 + quad * 4;
#pragma unroll
                for (int r = 0; r < 4; ++r) {
                    const int m  = mrow + r;
                    const int bb = m >> 13;
                    const int sq = m & (NSEQ - 1);
                    kt[(((size_t)(bb * NHEAD + h) * NSEQ + sq) << 7) + d] =
                        f2bf(acc[i][j][r] + bvals[j]);
                }
            }
        } else {
            // V transposed: [B][H][d][seq] -- short4 stores (4 consecutive seq)
            const int h = n >> 7;
            const int d = n & (HD - 1);
#pragma unroll
            for (int i = 0; i < 8; ++i) {
                const int mrow = M0 + wm * 128 + i * 16 + quad * 4;
                const int bb = mrow >> 13;
                const int sq = mrow & (NSEQ - 1);
                short4v o4;
#pragma unroll
                for (int r = 0; r < 4; ++r) o4[r] = f2bf(acc[i][j][r] + bvals[j]);
                *(short4v*)&vt[(((size_t)(bb * NHEAD + h) * HD + d) << 13) + sq] = o4;
            }
        }
    }
}

// ---------------------------------------------------------------------------
// Group-local causal attention (R4 verbatim): causal work-skip at 32-key-half
// granularity, wave w owns tiles {w, w+8}; chunk pipeline (K reg-prefetch +
// V global_load_lds dbuf), 2 barriers/chunk, wave-private Ps.
// ---------------------------------------------------------------------------
__global__ __launch_bounds__(512, 1) void s2_attn(const float* qsrc,   // aliases out!
                                                  const short* __restrict__ kt,
                                                  const short* __restrict__ vt,
                                                  float* out)
{
    __shared__ short Ks[64 * 136];       // K chunk, row-major, +8 pad
    __shared__ short Vt[2][128 * 64];    // V^T chunks: [d][kv], XOR-swizzled, dbuf
    __shared__ short Ps[8][32 * 40];     // per-wave P: 32 q-rows x 32 keys

    const int bx = blockIdx.x;
    const int g  = bx & 31;
    const int h  = (bx >> 5) & 15;
    const int b  = bx >> 9;
    const int shift = (h >= 8) ? 128 : 0;
    const int sbase = g * 256 + shift;   // group-local i -> seq p = (sbase+i)&8191

    const int tid  = threadIdx.x;
    const int wave = tid >> 6;
    const int lane = tid & 63;
    const int quad = lane >> 4;
    const int l15  = lane & 15;

    const size_t bh = ((size_t)b * NHEAD + h) * NSEQ;
    const short* kg = kt + bh * HD;
    const short* vg = vt + bh * HD;      // base of [d][seq] block for (b,h)

    // wave w owns m-tiles w (im=0) and w+8 (im=1)
    const int mtA = wave;
    const int mtB = wave + 8;

    const int vrow_in_w = lane >> 3;                       // == d&7
    const int vgcol     = ((lane & 7) * 8) ^ (vrow_in_w << 3);
    const int krow0 = tid >> 4;          // rows krow0 and krow0+32
    const int kcolb = (tid & 15) * 8;

    short8 kr0, kr1;                     // K prefetch registers (static names)

    // --- prologue: issue chunk-0 V async + K reg loads, then Q frags ---
    {
        const int p = (sbase + vgcol) & (NSEQ - 1);
#pragma unroll
        for (int c = 0; c < 2; c++) {
            const int d = c * 64 + wave * 8 + vrow_in_w;
            async_load16(vg + (size_t)d * NSEQ + p, &Vt[0][(c * 64 + wave * 8) * 64]);
        }
        const int p0 = (sbase + krow0) & (NSEQ - 1);
        const int p1 = (sbase + krow0 + 32) & (NSEQ - 1);
        kr0 = *(const short8*)(kg + (size_t)p0 * HD + kcolb);
        kr1 = *(const short8*)(kg + (size_t)p1 * HD + kcolb);
    }

    // Q fragments from fp32 d_out (A-layout: m=l15, k=quad*8+j)
    short8 qf[2][4];
#pragma unroll
    for (int im = 0; im < 2; im++) {
        const int mt  = im ? mtB : mtA;
        const int row = mt * 16 + l15;
        const int p   = (sbase + row) & (NSEQ - 1);
        const float* qr = qsrc + (((size_t)(b * NSEQ + p)) << 11) + h * HD;
#pragma unroll
        for (int ks = 0; ks < 4; ks++) {
            const float4v qa = *(const float4v*)(qr + ks * 32 + quad * 8);
            const float4v qb = *(const float4v*)(qr + ks * 32 + quad * 8 + 4);
            short8 f;
#pragma unroll
            for (int j = 0; j < 4; j++) { f[j] = f2bf(qa[j]); f[4 + j] = f2bf(qb[j]); }
            qf[im][ks] = f;
        }
    }

    const float4v fzero = {0.f, 0.f, 0.f, 0.f};
    float4v o[2][8];
#pragma unroll
    for (int im = 0; im < 2; im++)
#pragma unroll
        for (int dt = 0; dt < 8; dt++)
            o[im][dt] = fzero;
    float rs[2][4] = {{0.f, 0.f, 0.f, 0.f}, {0.f, 0.f, 0.f, 0.f}};

    for (int kc = 0; kc < 4; kc++) {
        // --- chunk top: V[kc] (LDS) and K[kc] (regs) needed now; latency
        // was hidden under chunk kc-1's compute. ---
        VMC0();
        *(short8*)&Ks[krow0 * 136 + kcolb]        = kr0;
        *(short8*)&Ks[(krow0 + 32) * 136 + kcolb] = kr1;
        LGKM0();
        PBAR();                          // all waves: Ks written, V[kc] in LDS

        // --- prefetch chunk kc+1 (V async into other buffer; K into regs) ---
        if (kc < 3) {
            const int p = (sbase + (kc + 1) * 64 + vgcol) & (NSEQ - 1);
#pragma unroll
            for (int c = 0; c < 2; c++) {
                const int d = c * 64 + wave * 8 + vrow_in_w;
                async_load16(vg + (size_t)d * NSEQ + p,
                             &Vt[(kc + 1) & 1][(c * 64 + wave * 8) * 64]);
            }
            const int p0 = (sbase + (kc + 1) * 64 + krow0) & (NSEQ - 1);
            const int p1 = (sbase + (kc + 1) * 64 + krow0 + 32) & (NSEQ - 1);
            kr0 = *(const short8*)(kg + (size_t)p0 * HD + kcolb);
            kr1 = *(const short8*)(kg + (size_t)p1 * HD + kcolb);
        }

        // half-unit activity (wave-uniform): u = 4kc + 2h <= mt
        const bool hA[2] = {(4 * kc)     <= mtA, (4 * kc + 2) <= mtA};
        const bool hB[2] = {(4 * kc)     <= mtB, (4 * kc + 2) <= mtB};

        // --- scores (half-aligned skip; mtB superset of mtA) ---
        float4v s[2][4];
#pragma unroll
        for (int im = 0; im < 2; im++)
#pragma unroll
            for (int nn = 0; nn < 4; nn++)
                s[im][nn] = fzero;
        __builtin_amdgcn_s_setprio(1);
#pragma unroll
        for (int nn = 0; nn < 4; nn++) {
            const int hh = nn >> 1;
            if (hB[hh]) {
                short8 kf[4];
#pragma unroll
                for (int ks = 0; ks < 4; ks++)
                    kf[ks] = *(const short8*)&Ks[(nn * 16 + l15) * 136 + ks * 32 + quad * 8];
                if (hA[hh]) {
#pragma unroll
                    for (int ks = 0; ks < 4; ks++)
                        s[0][nn] = __builtin_amdgcn_mfma_f32_16x16x32_bf16(
                            qf[0][ks], kf[ks], s[0][nn], 0, 0, 0);
                }
#pragma unroll
                for (int ks = 0; ks < 4; ks++)
                    s[1][nn] = __builtin_amdgcn_mfma_f32_16x16x32_bf16(
                        qf[1][ks], kf[ks], s[1][nn], 0, 0, 0);
            }
        }
        __builtin_amdgcn_s_setprio(0);

        // --- exp + P (wave-private LDS) + PV, per active 32-key half ---
#pragma unroll
        for (int half = 0; half < 2; half++) {
            if (!hB[half]) continue;     // hB superset of hA
#pragma unroll
            for (int im = 0; im < 2; im++) {
                if (im == 0 && !hA[half]) continue;
                const int mt   = im ? mtB : mtA;
                const int qpos = mt * 16 + quad * 4;               // group-abs q row (+r)
#pragma unroll
                for (int nn2 = 0; nn2 < 2; nn2++) {
                    const int nn   = half * 2 + nn2;
                    const int kpos = kc * 64 + nn * 16 + l15;      // group-abs key
#pragma unroll
                    for (int r = 0; r < 4; r++) {
                        const float sv = s[im][nn][r] * 0.088388347648318447f;
                        const float pv = (kpos > qpos + r)
                                             ? 0.f
                                             : __expf(fminf(sv, 30.f));
                        rs[im][r] += pv;
                        Ps[wave][(im * 16 + quad * 4 + r) * 40 + nn2 * 16 + l15] = f2bf(pv);
                    }
                }
            }
            LGKM0();                     // wave-private Ps: writes -> reads
            short8 pf[2];
            if (hA[half])
                pf[0] = *(const short8*)&Ps[wave][(0 * 16 + l15) * 40 + quad * 8];
            pf[1] = *(const short8*)&Ps[wave][(1 * 16 + l15) * 40 + quad * 8];
            __builtin_amdgcn_s_setprio(1);
#pragma unroll
            for (int dt = 0; dt < 8; dt++) {
                const int d = dt * 16 + l15;        // d&7 == l15&7
                const short8 vf = *(const short8*)
                    &Vt[kc & 1][d * 64 + ((half * 32 + quad * 8) ^ ((l15 & 7) << 3))];
                if (hA[half])
                    o[0][dt] = __builtin_amdgcn_mfma_f32_16x16x32_bf16(
                        pf[0], vf, o[0][dt], 0, 0, 0);
                o[1][dt] = __builtin_amdgcn_mfma_f32_16x16x32_bf16(
                    pf[1], vf, o[1][dt], 0, 0, 0);
            }
            __builtin_amdgcn_s_setprio(0);
        }
        PBAR();                          // chunk end: Ks readers done, V[kc] done
    }

    // row sums: reduce across the 16 l15 lanes of each quad
#pragma unroll
    for (int im = 0; im < 2; im++)
#pragma unroll
        for (int r = 0; r < 4; r++) {
            float v = rs[im][r];
            v += __shfl_xor(v, 1);
            v += __shfl_xor(v, 2);
            v += __shfl_xor(v, 4);
            v += __shfl_xor(v, 8);
            rs[im][r] = v;
        }

    // write output fp32 [B][N][C]; un-shift == same p mapping
#pragma unroll
    for (int im = 0; im < 2; im++) {
        const int mt = im ? mtB : mtA;
#pragma unroll
        for (int r = 0; r < 4; r++) {
            const int row = mt * 16 + quad * 4 + r;
            const int p   = (sbase + row) & (NSEQ - 1);
            const float inv = 1.f / rs[im][r];
            const size_t obase = (((size_t)(b * NSEQ + p)) << 11) + h * HD;
#pragma unroll
            for (int dt = 0; dt < 8; dt++)
                out[obase + dt * 16 + l15] = o[im][dt][r] * inv;
        }
    }
}

extern "C" void kernel_launch(void* const* d_in, const int* in_sizes, int n_in,
                              void* d_out, int out_size, void* d_ws, size_t ws_size,
                              hipStream_t stream) {
    (void)in_sizes; (void)n_in; (void)out_size; (void)ws_size;
    const float* x  = (const float*)d_in[0];
    const float* Wq = (const float*)d_in[1];
    const float* bq = (const float*)d_in[2];
    const float* Wk = (const float*)d_in[3];
    const float* bk = (const float*)d_in[4];
    const float* Wv = (const float*)d_in[5];
    const float* bv = (const float*)d_in[6];

    // ws layout (bf16 shorts): xb | wqb | wkb | wvb | kt | vt  (~216 MiB)
    short* xb  = (short*)d_ws;
    short* wqb = xb  + (size_t)33554432;
    short* wkb = wqb + (size_t)4194304;
    short* wvb = wkb + (size_t)4194304;
    short* kt  = wvb + (size_t)4194304;
    short* vt  = kt  + (size_t)33554432;

    float* outp = (float*)d_out;

    cvt_all<<<dim3(2048), 256, 0, stream>>>(x, Wq, Wk, Wv, xb, wqb, wkb, wvb);
    qkv_gemm8<<<dim3(1536), 512, 0, stream>>>(xb, wqb, bq, wkb, bk, wvb, bv,
                                              outp, kt, vt);
    s2_attn<<<dim3(1024), 512, 0, stream>>>(outp, kt, vt, outp);
}